// Round 3
// baseline (263.818 us; speedup 1.0000x reference)
//
#include <hip/hip_runtime.h>
#include <hip/hip_bf16.h>

#define NB 32
#define NA 1024
#define ND 128
#define TG 32

__device__ __forceinline__ float gelu_exact(float x) {
    return 0.5f * x * (1.0f + erff(x * 0.7071067811865476f));
}

// ---------------- clustering: one wave per batch, stride-interleaved ----------
// Point i -> lane i%64, slot i/64. Greedy order = slot-major = index order.
// Block NB computes the MLP(0) row (used by the mlp fast path).
__global__ __launch_bounds__(64) void cluster_kernel(
    const float2* __restrict__ coords, const int* __restrict__ mask,
    int* __restrict__ assigned, int* __restrict__ gcount,
    float* __restrict__ out_mask, float* __restrict__ out_a2g,
    const float* __restrict__ b1, const float* __restrict__ W2,
    const float* __restrict__ b2, float* __restrict__ empty_row)
{
    const int lane = threadIdx.x;

    if (blockIdx.x == NB) {
        // empty row = gelu(b1) @ W2 + b2   (runs concurrently with clustering)
        __shared__ float h0s[ND];
        h0s[lane]      = gelu_exact(b1[lane]);
        h0s[lane + 64] = gelu_exact(b1[lane + 64]);
        __syncthreads();
        float a0 = b2[lane], a1 = b2[lane + 64];
        for (int k = 0; k < ND; ++k) {
            float h = h0s[k];
            a0 += h * W2[k * ND + lane];
            a1 += h * W2[k * ND + lane + 64];
        }
        empty_row[lane]      = a0;
        empty_row[lane + 64] = a1;
        return;
    }

    const int b = blockIdx.x;
    const float2* cb = coords + (b << 10);
    const int*    mb = mask + (b << 10);

    float2 cxy[16];
    int asg[16];
    unsigned m = 0;
#pragma unroll
    for (int s = 0; s < 16; ++s) {
        cxy[s] = cb[s * 64 + lane];          // coalesced 512B per slot
        int v = mb[s * 64 + lane];
        asg[s] = v ? -1 : -2;
        m |= (v ? 1u : 0u) << s;
    }

    const float thr2 = 0.05f * 0.05f;
    int gid = 0;
#pragma unroll
    for (int s = 0; s < 16; ++s) {
        unsigned long long cand = __ballot((m >> s) & 1u);
        while (cand) {
            int L = (int)__builtin_ctzll(cand);          // wave-uniform (SGPR)
            float lx = __builtin_bit_cast(float,
                __builtin_amdgcn_readlane(__builtin_bit_cast(int, cxy[s].x), L));
            float ly = __builtin_bit_cast(float,
                __builtin_amdgcn_readlane(__builtin_bit_cast(int, cxy[s].y), L));
            unsigned take = 0u;
#pragma unroll
            for (int t = s; t < 16; ++t) {
                float dx = cxy[t].x - lx;
                float dy = cxy[t].y - ly;
                // exact mul+add (no fma contraction), matches np ref
                float d2 = __fadd_rn(__fmul_rn(dx, dx), __fmul_rn(dy, dy));
                bool tk = (d2 < thr2) && ((m >> t) & 1u);
                if (tk) asg[t] = gid;
                take |= (tk ? 1u : 0u) << t;
            }
            m &= ~take;
            ++gid;
            cand = __ballot((m >> s) & 1u);
        }
    }

    int*   ab = assigned + (b << 10);
    float* o2 = out_a2g + (b << 10);
    float* o1 = out_mask + (b << 10);
#pragma unroll
    for (int s = 0; s < 16; ++s) {
        int i = s * 64 + lane;
        ab[i] = asg[s];
        o2[i] = (asg[s] == -2) ? -1.0f : (float)asg[s];
        o1[i] = (i < gid) ? 1.0f : 0.0f;
    }
    if (lane == 0) gcount[b] = gid;
}

// ------------- fused pool (member-list + LDS atomics) + mean + 2-layer MLP ----
__global__ __launch_bounds__(256) void mlp_kernel(
    const float* __restrict__ emb, const int* __restrict__ assigned,
    const int* __restrict__ gcount, const float* __restrict__ empty_row,
    const float4* __restrict__ W1, const float* __restrict__ b1,
    const float4* __restrict__ W2, const float* __restrict__ b2,
    float* __restrict__ out0)
{
    const int b = blockIdx.y;
    const int g0 = blockIdx.x * TG;
    const int tid = threadIdx.x;
    const int G = gcount[b];
    float* ob = out0 + ((size_t)(b << 10) + g0) * ND;

    if (g0 >= G) {
        // rows past the last group are exactly MLP(0)
        float4 r = ((const float4*)empty_row)[tid & 31];
        float4* ob4 = (float4*)ob;
#pragma unroll
        for (int i = 0; i < 4; ++i) ob4[tid + i * 256] = r;
        return;
    }

    __shared__ float tokh[TG][ND];   // 16 KB: tokens, then h
    __shared__ int   mlist[NA];      // 4 KB: packed (a<<5 | g-g0)
    __shared__ float cnt[TG];
    __shared__ int   nmem;

#pragma unroll
    for (int i = 0; i < 16; ++i) ((float*)tokh)[tid + i * 256] = 0.0f;
    if (tid < TG) cnt[tid] = 0.0f;
    if (tid == 0) nmem = 0;
    __syncthreads();

    const int* ab = assigned + (b << 10);
    int4 av = ((const int4*)ab)[tid];
    const int aBase = tid * 4;
#pragma unroll
    for (int q = 0; q < 4; ++q) {
        int gv = (q == 0 ? av.x : q == 1 ? av.y : q == 2 ? av.z : av.w) - g0;
        if ((unsigned)gv < (unsigned)TG) {
            atomicAdd(&cnt[gv], 1.0f);
            int ix = atomicAdd(&nmem, 1);
            mlist[ix] = ((aBase + q) << 5) | gv;
        }
    }
    __syncthreads();

    const int NM = nmem;
    const int half = tid >> 7;          // 2 agents per iteration
    const int d = tid & 127;
    const float* eb = emb + ((size_t)(b << 10)) * ND;
    for (int i = half; i < NM; i += 2) {
        int pk = mlist[i];
        int a = pk >> 5, g = pk & 31;
        float v = eb[(size_t)a * ND + d];   // coalesced 512B per agent
        atomicAdd(&tokh[g][d], v);          // ds_add_f32
    }
    __syncthreads();

    // means
#pragma unroll
    for (int i = 0; i < 16; ++i) {
        int l = tid + i * 256;
        ((float*)tokh)[l] = ((float*)tokh)[l] / fmaxf(cnt[l >> 7], 1.0f);
    }
    __syncthreads();

    const int jq = tid & 31;   // output quad j = jq*4
    const int gs = tid >> 5;   // token rows gs, gs+8, gs+16, gs+24
    float acc[4][4];

    // ---- layer 1 (W1 straight from L2) ----
#pragma unroll
    for (int t = 0; t < 4; ++t)
#pragma unroll
        for (int jj = 0; jj < 4; ++jj) acc[t][jj] = 0.0f;

#pragma unroll 4
    for (int dd = 0; dd < ND; ++dd) {
        float4 w = W1[dd * 32 + jq];
#pragma unroll
        for (int t = 0; t < 4; ++t) {
            float tv = tokh[gs + t * 8][dd];
            acc[t][0] += tv * w.x;
            acc[t][1] += tv * w.y;
            acc[t][2] += tv * w.z;
            acc[t][3] += tv * w.w;
        }
    }
    float4 bb = ((const float4*)b1)[jq];
    __syncthreads();   // all layer-1 token reads done before overwrite
#pragma unroll
    for (int t = 0; t < 4; ++t) {
        float4 h;
        h.x = gelu_exact(acc[t][0] + bb.x);
        h.y = gelu_exact(acc[t][1] + bb.y);
        h.z = gelu_exact(acc[t][2] + bb.z);
        h.w = gelu_exact(acc[t][3] + bb.w);
        *(float4*)&tokh[gs + t * 8][jq * 4] = h;
    }
    __syncthreads();

    // ---- layer 2 ----
#pragma unroll
    for (int t = 0; t < 4; ++t)
#pragma unroll
        for (int jj = 0; jj < 4; ++jj) acc[t][jj] = 0.0f;

#pragma unroll 4
    for (int dd = 0; dd < ND; ++dd) {
        float4 w = W2[dd * 32 + jq];
#pragma unroll
        for (int t = 0; t < 4; ++t) {
            float tv = tokh[gs + t * 8][dd];
            acc[t][0] += tv * w.x;
            acc[t][1] += tv * w.y;
            acc[t][2] += tv * w.z;
            acc[t][3] += tv * w.w;
        }
    }
    float4 cbv = ((const float4*)b2)[jq];
#pragma unroll
    for (int t = 0; t < 4; ++t) {
        float4 o;
        o.x = acc[t][0] + cbv.x;
        o.y = acc[t][1] + cbv.y;
        o.z = acc[t][2] + cbv.z;
        o.w = acc[t][3] + cbv.w;
        *(float4*)&ob[(size_t)(gs + t * 8) * ND + jq * 4] = o;
    }
}

extern "C" void kernel_launch(void* const* d_in, const int* in_sizes, int n_in,
                              void* d_out, int out_size, void* d_ws, size_t ws_size,
                              hipStream_t stream) {
    const float* emb    = (const float*)d_in[0];   // [B,A,D]
    const float* coords = (const float*)d_in[1];   // [B,A,2]
    const int*   mask   = (const int*)d_in[2];     // [B,A]
    const float* W1     = (const float*)d_in[3];   // [D,D]
    const float* b1     = (const float*)d_in[4];   // [D]
    const float* W2     = (const float*)d_in[5];   // [D,D]
    const float* b2     = (const float*)d_in[6];   // [D]

    float* out0 = (float*)d_out;                    // [B,A,D]
    float* out1 = out0 + (size_t)NB * NA * ND;      // group_mask
    float* out2 = out1 + (size_t)NB * NA;           // agent_to_group

    // workspace: assigned, gcount, empty_row
    int*   ws_asg   = (int*)d_ws;                   // B*A
    int*   ws_gcnt  = ws_asg + (size_t)NB * NA;     // B
    float* ws_empty = (float*)(ws_gcnt + NB);       // D

    cluster_kernel<<<NB + 1, 64, 0, stream>>>(
        (const float2*)coords, mask, ws_asg, ws_gcnt, out1, out2,
        b1, W2, b2, ws_empty);
    mlp_kernel<<<dim3(NA / TG, NB), 256, 0, stream>>>(
        emb, ws_asg, ws_gcnt, ws_empty,
        (const float4*)W1, b1, (const float4*)W2, b2, out0);
}

// Round 5
// 177.543 us; speedup vs baseline: 1.4859x; 1.4859x over previous
//
#include <hip/hip_runtime.h>
#include <hip/hip_bf16.h>

#define NB 32
#define NA 1024
#define ND 128
#define TG 16

__device__ __forceinline__ float gelu_exact(float x) {
    return 0.5f * x * (1.0f + erff(x * 0.7071067811865476f));
}

// ---------------- clustering: one wave per batch, stride-interleaved ----------
// Point i -> lane i%64, slot i/64. Greedy order = slot-major = index order.
// launch_bounds(64,1): allow full VGPR budget so cxy[16]+asg[16] stay in regs.
// Block NB computes the MLP(0) row concurrently.
__global__ __launch_bounds__(64, 1) void cluster_kernel(
    const float2* __restrict__ coords, const int* __restrict__ mask,
    int* __restrict__ assigned, int* __restrict__ gcount,
    float* __restrict__ out_mask, float* __restrict__ out_a2g,
    const float* __restrict__ b1, const float* __restrict__ W2,
    const float* __restrict__ b2, float* __restrict__ empty_row)
{
    const int lane = threadIdx.x;

    if (blockIdx.x == NB) {
        // empty row = gelu(b1) @ W2 + b2
        __shared__ float h0s[ND];
        h0s[lane]      = gelu_exact(b1[lane]);
        h0s[lane + 64] = gelu_exact(b1[lane + 64]);
        __syncthreads();
        float a0 = b2[lane], a1 = b2[lane + 64];
        for (int k = 0; k < ND; ++k) {
            float h = h0s[k];
            a0 += h * W2[k * ND + lane];
            a1 += h * W2[k * ND + lane + 64];
        }
        empty_row[lane]      = a0;
        empty_row[lane + 64] = a1;
        return;
    }

    const int b = blockIdx.x;
    const float2* cb = coords + (b << 10);
    const int*    mb = mask + (b << 10);

    float2 cxy[16];
    int asg[16];
    unsigned m = 0;
#pragma unroll
    for (int s = 0; s < 16; ++s) {
        cxy[s] = cb[s * 64 + lane];          // coalesced 512B per slot
        int v = mb[s * 64 + lane];
        asg[s] = v ? -1 : -2;
        m |= (v ? 1u : 0u) << s;
    }

    const float thr2 = 0.05f * 0.05f;
    int gid = 0;
#pragma unroll
    for (int s = 0; s < 16; ++s) {
        unsigned long long cand = __ballot((m >> s) & 1u);
        while (cand) {
            int L = (int)__builtin_ctzll(cand);          // wave-uniform (SGPR)
            float lx = __builtin_bit_cast(float,
                __builtin_amdgcn_readlane(__builtin_bit_cast(int, cxy[s].x), L));
            float ly = __builtin_bit_cast(float,
                __builtin_amdgcn_readlane(__builtin_bit_cast(int, cxy[s].y), L));
            unsigned take = 0u;
#pragma unroll
            for (int t = s; t < 16; ++t) {
                float dx = cxy[t].x - lx;
                float dy = cxy[t].y - ly;
                // exact mul+add (no fma contraction), matches np ref
                float d2 = __fadd_rn(__fmul_rn(dx, dx), __fmul_rn(dy, dy));
                bool tk = (d2 < thr2) && ((m >> t) & 1u);
                if (tk) asg[t] = gid;
                take |= (tk ? 1u : 0u) << t;
            }
            m &= ~take;
            ++gid;
            cand = __ballot((m >> s) & 1u);
        }
    }

    int*   ab = assigned + (b << 10);
    float* o2 = out_a2g + (b << 10);
    float* o1 = out_mask + (b << 10);
#pragma unroll
    for (int s = 0; s < 16; ++s) {
        int i = s * 64 + lane;
        ab[i] = asg[s];
        o2[i] = (asg[s] == -2) ? -1.0f : (float)asg[s];
        o1[i] = (i < gid) ? 1.0f : 0.0f;
    }
    if (lane == 0) gcount[b] = gid;
}

// ---------------- CSR build: one block per batch ------------------------------
__global__ __launch_bounds__(256) void csr_kernel(
    const int* __restrict__ assigned,
    int* __restrict__ memb, int* __restrict__ goff, float* __restrict__ gcntf)
{
    const int b = blockIdx.x;
    const int tid = threadIdx.x;
    __shared__ int cnt[NA];
    __shared__ int sA[NA];
    __shared__ int sB[NA];
    __shared__ int cur[NA];

    for (int i = tid; i < NA; i += 256) cnt[i] = 0;
    __syncthreads();

    const int4 av = ((const int4*)(assigned + (b << 10)))[tid];
    if (av.x >= 0) atomicAdd(&cnt[av.x], 1);
    if (av.y >= 0) atomicAdd(&cnt[av.y], 1);
    if (av.z >= 0) atomicAdd(&cnt[av.z], 1);
    if (av.w >= 0) atomicAdd(&cnt[av.w], 1);
    __syncthreads();

    // inclusive scan (Hillis-Steele, double-buffered)
    for (int i = tid; i < NA; i += 256) sA[i] = cnt[i];
    __syncthreads();
    int* src = sA; int* dst = sB;
    for (int d = 1; d < NA; d <<= 1) {
        for (int i = tid; i < NA; i += 256) {
            int v = src[i];
            if (i >= d) v += src[i - d];
            dst[i] = v;
        }
        __syncthreads();
        int* t = src; src = dst; dst = t;
    }
    for (int i = tid; i < NA; i += 256) cur[i] = src[i] - cnt[i];  // exclusive
    __syncthreads();
    for (int i = tid; i < NA; i += 256) {
        goff[(b << 10) + i]  = cur[i];
        gcntf[(b << 10) + i] = (float)cnt[i];
    }
    __syncthreads();   // goff written before cur is consumed by scatter

    const int a = tid * 4;
    if (av.x >= 0) { int p = atomicAdd(&cur[av.x], 1); memb[(b << 10) + p] = a; }
    if (av.y >= 0) { int p = atomicAdd(&cur[av.y], 1); memb[(b << 10) + p] = a + 1; }
    if (av.z >= 0) { int p = atomicAdd(&cur[av.z], 1); memb[(b << 10) + p] = a + 2; }
    if (av.w >= 0) { int p = atomicAdd(&cur[av.w], 1); memb[(b << 10) + p] = a + 3; }
}

// ---------------- token means: 16 threads per group, register accumulate ------
__global__ __launch_bounds__(256) void token_kernel(
    const float* __restrict__ emb, const int* __restrict__ memb,
    const int* __restrict__ goff, const float* __restrict__ gcntf,
    const int* __restrict__ gcount, float* __restrict__ tokens)
{
    const int b = blockIdx.y;
    if (blockIdx.x * TG >= gcount[b]) return;
    const int g = blockIdx.x * TG + (threadIdx.x >> 4);
    const int sub = threadIdx.x & 15;

    const int off = goff[(b << 10) + g];
    const int n   = (int)gcntf[(b << 10) + g];      // 0 for g >= G in last chunk
    const int* mb = memb + (b << 10) + off;
    const float* eb = emb + ((size_t)(b << 10)) * ND + sub * 8;

    float acc[8];
#pragma unroll
    for (int j = 0; j < 8; ++j) acc[j] = 0.0f;
    for (int k = 0; k < n; ++k) {
        int a = mb[k];
        const float4* e4 = (const float4*)(eb + (size_t)a * ND);
        float4 v0 = e4[0], v1 = e4[1];
        acc[0] += v0.x; acc[1] += v0.y; acc[2] += v0.z; acc[3] += v0.w;
        acc[4] += v1.x; acc[5] += v1.y; acc[6] += v1.z; acc[7] += v1.w;
    }
    const float den = fmaxf((float)n, 1.0f);
    float4 t0, t1;
    t0.x = acc[0] / den; t0.y = acc[1] / den; t0.z = acc[2] / den; t0.w = acc[3] / den;
    t1.x = acc[4] / den; t1.y = acc[5] / den; t1.z = acc[6] / den; t1.w = acc[7] / den;
    float4* tout = (float4*)(tokens + (((size_t)(b << 10)) + g) * ND + sub * 8);
    tout[0] = t0; tout[1] = t1;
}

// ---------------- 2-layer MLP, TG=16 tokens per block -------------------------
__global__ __launch_bounds__(256, 2) void mlp_kernel(
    const float* __restrict__ tokens, const int* __restrict__ gcount,
    const float* __restrict__ empty_row,
    const float4* __restrict__ W1, const float* __restrict__ b1,
    const float4* __restrict__ W2, const float* __restrict__ b2,
    float* __restrict__ out0)
{
    const int b = blockIdx.y;
    const int g0 = blockIdx.x * TG;
    const int tid = threadIdx.x;
    float* ob = out0 + ((size_t)(b << 10) + g0) * ND;

    if (g0 >= gcount[b]) {
        float4 r = ((const float4*)empty_row)[tid & 31];
        float4* ob4 = (float4*)ob;
        ob4[tid] = r;
        ob4[tid + 256] = r;
        return;
    }

    __shared__ float4 Wl[4096];      // 64 KB
    __shared__ float tok[TG][ND];    // 8 KB: tokens, then h

    {
        const float4* tsrc = (const float4*)(tokens + ((size_t)(b << 10) + g0) * ND);
        float4* tdst = (float4*)&tok[0][0];
        tdst[tid] = tsrc[tid];
        tdst[tid + 256] = tsrc[tid + 256];
    }
#pragma unroll
    for (int i = 0; i < 16; ++i) Wl[tid + i * 256] = W1[tid + i * 256];
    __syncthreads();

    const int jq = tid & 31;   // output quad j = jq*4
    const int gs = tid >> 5;   // token rows gs, gs+8
    float acc[2][4];
#pragma unroll
    for (int jj = 0; jj < 4; ++jj) { acc[0][jj] = 0.0f; acc[1][jj] = 0.0f; }

#pragma unroll 4
    for (int dd = 0; dd < ND; ++dd) {
        float4 w = Wl[dd * 32 + jq];
        float t0 = tok[gs][dd];
        float t1 = tok[gs + 8][dd];
        acc[0][0] += t0 * w.x; acc[0][1] += t0 * w.y;
        acc[0][2] += t0 * w.z; acc[0][3] += t0 * w.w;
        acc[1][0] += t1 * w.x; acc[1][1] += t1 * w.y;
        acc[1][2] += t1 * w.z; acc[1][3] += t1 * w.w;
    }
    float4 bb = ((const float4*)b1)[jq];
    __syncthreads();   // all layer-1 tok/Wl reads done
    {
        float4 h;
        h.x = gelu_exact(acc[0][0] + bb.x);
        h.y = gelu_exact(acc[0][1] + bb.y);
        h.z = gelu_exact(acc[0][2] + bb.z);
        h.w = gelu_exact(acc[0][3] + bb.w);
        *(float4*)&tok[gs][jq * 4] = h;
        h.x = gelu_exact(acc[1][0] + bb.x);
        h.y = gelu_exact(acc[1][1] + bb.y);
        h.z = gelu_exact(acc[1][2] + bb.z);
        h.w = gelu_exact(acc[1][3] + bb.w);
        *(float4*)&tok[gs + 8][jq * 4] = h;
    }
#pragma unroll
    for (int i = 0; i < 16; ++i) Wl[tid + i * 256] = W2[tid + i * 256];
    __syncthreads();

#pragma unroll
    for (int jj = 0; jj < 4; ++jj) { acc[0][jj] = 0.0f; acc[1][jj] = 0.0f; }
#pragma unroll 4
    for (int dd = 0; dd < ND; ++dd) {
        float4 w = Wl[dd * 32 + jq];
        float t0 = tok[gs][dd];
        float t1 = tok[gs + 8][dd];
        acc[0][0] += t0 * w.x; acc[0][1] += t0 * w.y;
        acc[0][2] += t0 * w.z; acc[0][3] += t0 * w.w;
        acc[1][0] += t1 * w.x; acc[1][1] += t1 * w.y;
        acc[1][2] += t1 * w.z; acc[1][3] += t1 * w.w;
    }
    float4 cbv = ((const float4*)b2)[jq];
    {
        float4 o;
        o.x = acc[0][0] + cbv.x; o.y = acc[0][1] + cbv.y;
        o.z = acc[0][2] + cbv.z; o.w = acc[0][3] + cbv.w;
        *(float4*)&ob[(size_t)gs * ND + jq * 4] = o;
        o.x = acc[1][0] + cbv.x; o.y = acc[1][1] + cbv.y;
        o.z = acc[1][2] + cbv.z; o.w = acc[1][3] + cbv.w;
        *(float4*)&ob[(size_t)(gs + 8) * ND + jq * 4] = o;
    }
}

extern "C" void kernel_launch(void* const* d_in, const int* in_sizes, int n_in,
                              void* d_out, int out_size, void* d_ws, size_t ws_size,
                              hipStream_t stream) {
    const float* emb    = (const float*)d_in[0];   // [B,A,D]
    const float* coords = (const float*)d_in[1];   // [B,A,2]
    const int*   mask   = (const int*)d_in[2];     // [B,A]
    const float* W1     = (const float*)d_in[3];   // [D,D]
    const float* b1     = (const float*)d_in[4];   // [D]
    const float* W2     = (const float*)d_in[5];   // [D,D]
    const float* b2     = (const float*)d_in[6];   // [D]

    float* out0 = (float*)d_out;                    // [B,A,D]
    float* out1 = out0 + (size_t)NB * NA * ND;      // group_mask
    float* out2 = out1 + (size_t)NB * NA;           // agent_to_group

    // workspace layout
    float* ws_tok   = (float*)d_ws;                       // B*A*D
    int*   ws_asg   = (int*)(ws_tok + (size_t)NB * NA * ND); // B*A
    int*   ws_memb  = ws_asg + (size_t)NB * NA;           // B*A
    int*   ws_goff  = ws_memb + (size_t)NB * NA;          // B*A
    float* ws_gcntf = (float*)(ws_goff + (size_t)NB * NA);// B*A
    int*   ws_gcnt  = (int*)(ws_gcntf + (size_t)NB * NA); // B
    float* ws_empty = (float*)(ws_gcnt + NB);             // D

    cluster_kernel<<<NB + 1, 64, 0, stream>>>(
        (const float2*)coords, mask, ws_asg, ws_gcnt, out1, out2,
        b1, W2, b2, ws_empty);
    csr_kernel<<<NB, 256, 0, stream>>>(ws_asg, ws_memb, ws_goff, ws_gcntf);
    token_kernel<<<dim3(NA / TG, NB), 256, 0, stream>>>(
        emb, ws_memb, ws_goff, ws_gcntf, ws_gcnt, ws_tok);
    mlp_kernel<<<dim3(NA / TG, NB), 256, 0, stream>>>(
        ws_tok, ws_gcnt, ws_empty,
        (const float4*)W1, b1, (const float4*)W2, b2, out0);
}

// Round 6
// 147.670 us; speedup vs baseline: 1.7865x; 1.2023x over previous
//
#include <hip/hip_runtime.h>
#include <hip/hip_bf16.h>

#define NB 32
#define NA 1024
#define ND 128
#define TG 16

__device__ __forceinline__ float gelu_exact(float x) {
    return 0.5f * x * (1.0f + erff(x * 0.7071067811865476f));
}

// ---------------------------------------------------------------------------
// Fused clustering + CSR + token means. One block of 1024 threads per batch.
// Point i -> wave i/64, lane i%64 (one point per lane: no arrays, no spills).
// Greedy absorption only affects later-indexed points, so wave w produces its
// slot's leaders after waves <w finish, while waves >w consume the leader
// stream concurrently from an LDS ring (producer/consumer pipeline).
// Block NB computes the MLP(0) row used by the mlp fast path.
// ---------------------------------------------------------------------------
__global__ __launch_bounds__(1024, 1) void fused_kernel(
    const float2* __restrict__ coords, const int* __restrict__ mask,
    const float* __restrict__ emb,
    int* __restrict__ gcount, float* __restrict__ tokens,
    float* __restrict__ out_mask, float* __restrict__ out_a2g,
    const float* __restrict__ b1, const float* __restrict__ W2,
    const float* __restrict__ b2, float* __restrict__ empty_row)
{
    __shared__ float2 ring[NA + 4];   // leader coords, gid = ring index
    __shared__ int cnt_s[NA];
    __shared__ int bufA[NA];
    __shared__ int bufB[NA];
    __shared__ int memb[NA];
    __shared__ int done_s[16];
    __shared__ int lead_cnt;

    const int tid = threadIdx.x;

    if (blockIdx.x == NB) {
        // empty row = gelu(b1) @ W2 + b2 (runs concurrently with clustering)
        float* hbuf = (float*)ring;
        if (tid < ND) hbuf[tid] = gelu_exact(b1[tid]);
        __syncthreads();
        if (tid < ND) {
            float acc = b2[tid];
            for (int k = 0; k < ND; ++k) acc += hbuf[k] * W2[k * ND + tid];
            empty_row[tid] = acc;
        }
        return;
    }

    const int b = blockIdx.x;
    const int w = tid >> 6;
    const int lane = tid & 63;

    if (tid < 16) done_s[tid] = -1;
    if (tid == 0) lead_cnt = 0;

    float2 p = coords[(b << 10) + tid];
    const bool valid = mask[(b << 10) + tid] != 0;
    int asg = valid ? -1 : -2;
    bool alive = valid;
    const float thr2 = 0.05f * 0.05f;

    __syncthreads();

    int seen = 0;
    int target = (w == 0) ? 0 : -1;

    // -------- consume earlier waves' leaders as they are published --------
    while (true) {
        int c = __hip_atomic_load(&lead_cnt, __ATOMIC_ACQUIRE,
                                  __HIP_MEMORY_SCOPE_WORKGROUP);
        while (seen < c) {
            float2 l0 = ring[seen];
            float2 l1 = ring[seen + 1];
            float2 l2 = ring[seen + 2];
            float2 l3 = ring[seen + 3];
            {
                float dx = p.x - l0.x, dy = p.y - l0.y;
                float d2 = __fadd_rn(__fmul_rn(dx, dx), __fmul_rn(dy, dy));
                if (alive && d2 < thr2) { asg = seen; alive = false; }
            }
            if (seen + 1 < c) {
                float dx = p.x - l1.x, dy = p.y - l1.y;
                float d2 = __fadd_rn(__fmul_rn(dx, dx), __fmul_rn(dy, dy));
                if (alive && d2 < thr2) { asg = seen + 1; alive = false; }
            }
            if (seen + 2 < c) {
                float dx = p.x - l2.x, dy = p.y - l2.y;
                float d2 = __fadd_rn(__fmul_rn(dx, dx), __fmul_rn(dy, dy));
                if (alive && d2 < thr2) { asg = seen + 2; alive = false; }
            }
            if (seen + 3 < c) {
                float dx = p.x - l3.x, dy = p.y - l3.y;
                float d2 = __fadd_rn(__fmul_rn(dx, dx), __fmul_rn(dy, dy));
                if (alive && d2 < thr2) { asg = seen + 3; alive = false; }
            }
            seen = (seen + 4 < c) ? seen + 4 : c;
        }
        if (target < 0)
            target = __hip_atomic_load(&done_s[w - 1], __ATOMIC_ACQUIRE,
                                       __HIP_MEMORY_SCOPE_WORKGROUP);
        if (target >= 0 && seen >= target) break;
        __builtin_amdgcn_s_sleep(1);
    }

    // -------- produce this wave's leaders --------
    __builtin_amdgcn_s_setprio(1);
    unsigned long long bal;
    while ((bal = __ballot(alive)) != 0ULL) {
        const int L = (int)__builtin_ctzll(bal);         // wave-uniform
        const float lx = __builtin_bit_cast(float,
            __builtin_amdgcn_readlane(__builtin_bit_cast(int, p.x), L));
        const float ly = __builtin_bit_cast(float,
            __builtin_amdgcn_readlane(__builtin_bit_cast(int, p.y), L));
        float dx = p.x - lx, dy = p.y - ly;
        float d2 = __fadd_rn(__fmul_rn(dx, dx), __fmul_rn(dy, dy));
        bool take = alive && (d2 < thr2);                // lane L: d2==0 -> take
        if (take) { asg = seen; alive = false; }
        if (lane == 0) {
            ring[seen] = make_float2(lx, ly);
            __hip_atomic_store(&lead_cnt, seen + 1, __ATOMIC_RELEASE,
                               __HIP_MEMORY_SCOPE_WORKGROUP);
        }
        ++seen;
    }
    __builtin_amdgcn_s_setprio(0);
    if (lane == 0)
        __hip_atomic_store(&done_s[w], seen, __ATOMIC_RELEASE,
                           __HIP_MEMORY_SCOPE_WORKGROUP);

    __syncthreads();
    const int G = lead_cnt;

    // -------- phase 2: CSR (counts, scan, scatter) --------
    cnt_s[tid] = 0;
    __syncthreads();
    if (asg >= 0) atomicAdd(&cnt_s[asg], 1);
    __syncthreads();

    bufA[tid] = cnt_s[tid];
    __syncthreads();
    int* src = bufA;
    int* dst = bufB;
    for (int d = 1; d < NA; d <<= 1) {      // 10 steps -> ends with src == bufA
        int v = src[tid];
        if (tid >= d) v += src[tid - d];
        dst[tid] = v;
        __syncthreads();
        int* tswap = src; src = dst; dst = tswap;
    }
    const int excl = src[tid] - cnt_s[tid];
    bufB[tid] = excl;    // group offsets (persist)
    bufA[tid] = excl;    // scatter cursor
    __syncthreads();
    if (asg >= 0) {
        int ppos = atomicAdd(&bufA[asg], 1);
        memb[ppos] = tid;
    }
    __syncthreads();

    // -------- per-agent outputs --------
    out_a2g[(b << 10) + tid] = (asg == -2) ? -1.0f : (float)asg;
    out_mask[(b << 10) + tid] = (tid < G) ? 1.0f : 0.0f;
    if (tid == 0) gcount[b] = G;

    // -------- token means (wave w: groups w, w+16, ...) --------
    const int Gpad = (G + TG - 1) & ~(TG - 1);
    const float* eb = emb + ((size_t)(b) << 10) * ND;
    float* tb = tokens + ((size_t)(b) << 10) * ND;
    for (int g = w; g < Gpad; g += 16) {
        float a0 = 0.0f, a1 = 0.0f;
        if (g < G) {
            const int n = cnt_s[g];
            const int off = bufB[g];
            for (int k = 0; k < n; ++k) {
                const int a = memb[off + k];
                const float* ea = eb + (size_t)a * ND;
                a0 += ea[lane];          // coalesced 256B per member
                a1 += ea[lane + 64];
            }
            const float den = fmaxf((float)n, 1.0f);
            a0 /= den; a1 /= den;
        }
        tb[(size_t)g * ND + lane] = a0;       // zero rows for g in [G, Gpad)
        tb[(size_t)g * ND + lane + 64] = a1;  // -> mlp computes MLP(0) there
    }
}

// ---------------- 2-layer MLP, TG=16 tokens per block (unchanged) ------------
__global__ __launch_bounds__(256, 2) void mlp_kernel(
    const float* __restrict__ tokens, const int* __restrict__ gcount,
    const float* __restrict__ empty_row,
    const float4* __restrict__ W1, const float* __restrict__ b1,
    const float4* __restrict__ W2, const float* __restrict__ b2,
    float* __restrict__ out0)
{
    const int b = blockIdx.y;
    const int g0 = blockIdx.x * TG;
    const int tid = threadIdx.x;
    float* ob = out0 + ((size_t)(b << 10) + g0) * ND;

    if (g0 >= gcount[b]) {
        float4 r = ((const float4*)empty_row)[tid & 31];
        float4* ob4 = (float4*)ob;
        ob4[tid] = r;
        ob4[tid + 256] = r;
        return;
    }

    __shared__ float4 Wl[4096];      // 64 KB
    __shared__ float tok[TG][ND];    // 8 KB: tokens, then h

    {
        const float4* tsrc = (const float4*)(tokens + ((size_t)(b << 10) + g0) * ND);
        float4* tdst = (float4*)&tok[0][0];
        tdst[tid] = tsrc[tid];
        tdst[tid + 256] = tsrc[tid + 256];
    }
#pragma unroll
    for (int i = 0; i < 16; ++i) Wl[tid + i * 256] = W1[tid + i * 256];
    __syncthreads();

    const int jq = tid & 31;
    const int gs = tid >> 5;
    float acc[2][4];
#pragma unroll
    for (int jj = 0; jj < 4; ++jj) { acc[0][jj] = 0.0f; acc[1][jj] = 0.0f; }

#pragma unroll 4
    for (int dd = 0; dd < ND; ++dd) {
        float4 wv = Wl[dd * 32 + jq];
        float t0 = tok[gs][dd];
        float t1 = tok[gs + 8][dd];
        acc[0][0] += t0 * wv.x; acc[0][1] += t0 * wv.y;
        acc[0][2] += t0 * wv.z; acc[0][3] += t0 * wv.w;
        acc[1][0] += t1 * wv.x; acc[1][1] += t1 * wv.y;
        acc[1][2] += t1 * wv.z; acc[1][3] += t1 * wv.w;
    }
    float4 bb = ((const float4*)b1)[jq];
    __syncthreads();
    {
        float4 h;
        h.x = gelu_exact(acc[0][0] + bb.x);
        h.y = gelu_exact(acc[0][1] + bb.y);
        h.z = gelu_exact(acc[0][2] + bb.z);
        h.w = gelu_exact(acc[0][3] + bb.w);
        *(float4*)&tok[gs][jq * 4] = h;
        h.x = gelu_exact(acc[1][0] + bb.x);
        h.y = gelu_exact(acc[1][1] + bb.y);
        h.z = gelu_exact(acc[1][2] + bb.z);
        h.w = gelu_exact(acc[1][3] + bb.w);
        *(float4*)&tok[gs + 8][jq * 4] = h;
    }
#pragma unroll
    for (int i = 0; i < 16; ++i) Wl[tid + i * 256] = W2[tid + i * 256];
    __syncthreads();

#pragma unroll
    for (int jj = 0; jj < 4; ++jj) { acc[0][jj] = 0.0f; acc[1][jj] = 0.0f; }
#pragma unroll 4
    for (int dd = 0; dd < ND; ++dd) {
        float4 wv = Wl[dd * 32 + jq];
        float t0 = tok[gs][dd];
        float t1 = tok[gs + 8][dd];
        acc[0][0] += t0 * wv.x; acc[0][1] += t0 * wv.y;
        acc[0][2] += t0 * wv.z; acc[0][3] += t0 * wv.w;
        acc[1][0] += t1 * wv.x; acc[1][1] += t1 * wv.y;
        acc[1][2] += t1 * wv.z; acc[1][3] += t1 * wv.w;
    }
    float4 cbv = ((const float4*)b2)[jq];
    {
        float4 o;
        o.x = acc[0][0] + cbv.x; o.y = acc[0][1] + cbv.y;
        o.z = acc[0][2] + cbv.z; o.w = acc[0][3] + cbv.w;
        *(float4*)&ob[(size_t)gs * ND + jq * 4] = o;
        o.x = acc[1][0] + cbv.x; o.y = acc[1][1] + cbv.y;
        o.z = acc[1][2] + cbv.z; o.w = acc[1][3] + cbv.w;
        *(float4*)&ob[(size_t)(gs + 8) * ND + jq * 4] = o;
    }
}

extern "C" void kernel_launch(void* const* d_in, const int* in_sizes, int n_in,
                              void* d_out, int out_size, void* d_ws, size_t ws_size,
                              hipStream_t stream) {
    const float* emb    = (const float*)d_in[0];   // [B,A,D]
    const float* coords = (const float*)d_in[1];   // [B,A,2]
    const int*   mask   = (const int*)d_in[2];     // [B,A]
    const float* W1     = (const float*)d_in[3];   // [D,D]
    const float* b1     = (const float*)d_in[4];   // [D]
    const float* W2     = (const float*)d_in[5];   // [D,D]
    const float* b2     = (const float*)d_in[6];   // [D]

    float* out0 = (float*)d_out;                    // [B,A,D]
    float* out1 = out0 + (size_t)NB * NA * ND;      // group_mask
    float* out2 = out1 + (size_t)NB * NA;           // agent_to_group

    // workspace: tokens, gcount, empty_row
    float* ws_tok   = (float*)d_ws;                       // B*A*D
    int*   ws_gcnt  = (int*)(ws_tok + (size_t)NB * NA * ND); // B
    float* ws_empty = (float*)(ws_gcnt + NB);             // D

    fused_kernel<<<NB + 1, 1024, 0, stream>>>(
        (const float2*)coords, mask, emb,
        ws_gcnt, ws_tok, out1, out2,
        b1, W2, b2, ws_empty);
    mlp_kernel<<<dim3(NA / TG, NB), 256, 0, stream>>>(
        ws_tok, ws_gcnt, ws_empty,
        (const float4*)W1, b1, (const float4*)W2, b2, out0);
}